// Round 14
// baseline (314.279 us; speedup 1.0000x reference)
//
#include <hip/hip_runtime.h>
#include <hip/hip_bf16.h>
#include <math.h>

#define B_ROWS 4096
#define N_ROWS 8192
#define D_DIM  128
#define SCALE_LOG2 2.8853900817779268f   // (1/T)*log2(e)
#define PRESCALE 1.6986436f              // sqrt(SCALE_LOG2), folded into rows
#define LN2_OVER_4 0.17328679513998632f  // converts 4x-dup group dot -> 2*cos

#define CSPLIT 64
#define NTILES 2080                      // 64*65/2 upper-triangle 128x128 tiles
#define NFIN   32                        // last-32 blocks run the finalize

typedef __bf16 bf16x8 __attribute__((ext_vector_type(8)));
typedef __bf16 bf16x2 __attribute__((ext_vector_type(2)));
typedef float  f32x16 __attribute__((ext_vector_type(16)));

#if __has_builtin(__builtin_amdgcn_exp2f)
#define EXP2F(x) __builtin_amdgcn_exp2f(x)
#else
#define EXP2F(x) exp2f(x)
#endif

#define AS(n) __attribute__((address_space(n)))

// Packed fragment-major layout (16B chunk units), 32x32x16 MFMA:
//   chunk(p, kk, l) = zn[p*32 + (l&31)][ (kk*2 + (l>>5))*8 .. +8 ]   (8 bf16)
//   addr16B = p*512 + kk*64 + l
// one wave fragment load = 64 consecutive 16B chunks = 1KB coalesced.

// ---------- K1: normalize rows of concat(z_i, z_j) -> packed bf16 ----------
// Block 0 also zeroes the output scalar and the completion counter (workspace
// is NOT re-poisoned between graph replays -> must re-zero every launch;
// the K1->K2 dispatch boundary guarantees visibility).
__global__ __launch_bounds__(256) void k_normalize(const float* __restrict__ zi,
                                                   const float* __restrict__ zj,
                                                   __bf16* __restrict__ pack,
                                                   float* __restrict__ out,
                                                   unsigned int* __restrict__ done) {
    if (blockIdx.x == 0 && threadIdx.x == 0) { out[0] = 0.0f; done[0] = 0u; }
    const int wid  = threadIdx.x >> 6;
    const int lane = threadIdx.x & 63;
    const int row  = blockIdx.x * 4 + wid;
    const float* src = (row < B_ROWS) ? (zi + (size_t)row * D_DIM)
                                      : (zj + (size_t)(row - B_ROWS) * D_DIM);
    float2 v = ((const float2*)src)[lane];
    float ss = v.x * v.x + v.y * v.y;
    #pragma unroll
    for (int off = 1; off < 64; off <<= 1) ss += __shfl_xor(ss, off, 64);
    float inv = PRESCALE / fmaxf(sqrtf(ss), 1e-8f);
    bf16x2 o;
    o[0] = (__bf16)(v.x * inv);
    o[1] = (__bf16)(v.y * inv);
    const int chunk = ((row >> 5) << 9) + ((lane >> 3) << 6) +
                      (((lane >> 2) & 1) << 5) + (row & 31);
    ((bf16x2*)pack)[chunk * 4 + (lane & 3)] = o;
}

// ---------- K2: upper-triangle NT-GEMM + fused finalize ----------
// Tile compute = R13 (async global_load_lds staging, one barrier, 4 chains,
// fused exp2, multi-value butterfly row-reduce, symmetric col-sums).
// After the tile: release-fence + atomicAdd(done). The last NFIN finishers
// spin until done==NTILES (thread-0 spin + s_sleep; 32 spinners << 1024
// co-resident slots so the scheduler keeps backfilling compute blocks),
// acquire-fence, then each finalizes a 256-row slice of the nll sum.
__global__ __launch_bounds__(256, 4) void k_gemm_expsum(const __bf16* __restrict__ pack,
                                                        float* __restrict__ partials,
                                                        unsigned int* __restrict__ done,
                                                        float* __restrict__ out) {
    // decode linear upper-tri index u -> (rb, cs): S(r) = 64r - r(r-1)/2
    const int u = blockIdx.x;
    int rb = (int)((129.0 - sqrt(16641.0 - 8.0 * (double)u)) * 0.5);
    if (rb < 0) rb = 0;
    if (rb > 63) rb = 63;
    while (rb > 0 && 64 * rb - rb * (rb - 1) / 2 > u) --rb;
    while (rb < 63 && 64 * (rb + 1) - (rb + 1) * rb / 2 <= u) ++rb;
    const int cs = rb + (u - (64 * rb - rb * (rb - 1) / 2));

    const int wid  = threadIdx.x >> 6;
    const int lane = threadIdx.x & 63;
    const int h    = lane >> 5;    // lane half (k-group)
    const int ln   = lane & 31;

    __shared__ __bf16 Bs[16384];   // 32 KB = 4 col-panels x 512 chunks x 16B
    __shared__ float  cls[4][128]; // per-wave column sums
    __shared__ unsigned int s_old;

    const bf16x8* pk = (const bf16x8*)pack;   // 16B chunk units

    // 1a. async-stage B panel: packed panels [4cs, 4cs+3] -> LDS, linear.
    {
        const size_t gbase = (size_t)cs * 2048;
        #pragma unroll
        for (int q = 0; q < 8; ++q) {
            const int cidx = q * 256 + wid * 64;   // wave-uniform chunk index
            __builtin_amdgcn_global_load_lds(
                (const AS(1) void*)(pk + gbase + cidx + lane),
                (AS(3) void*)(Bs + (size_t)cidx * 8), 16, 0, 0);
        }
    }

    // 1b. A fragments (private, coalesced) - in flight during B staging
    const int row0 = rb * 128 + wid * 32;
    const size_t pa = (size_t)(row0 >> 5) * 512;
    bf16x8 a[8];
    #pragma unroll
    for (int kk = 0; kk < 8; ++kk)
        a[kk] = pk[pa + kk * 64 + lane];

    float sums[16];
    #pragma unroll
    for (int i = 0; i < 16; ++i) sums[i] = 0.0f;
    float csum0 = 0.0f, csum1 = 0.0f, csum2 = 0.0f, csum3 = 0.0f;

    // 2. one barrier (drains vmcnt: global_load_lds + A loads)
    __syncthreads();

    // 3. four independent col-tile compute chains
    const bf16x8* bs8 = (const bf16x8*)Bs;
    #pragma unroll
    for (int c = 0; c < 4; ++c) {
        f32x16 acc = {};
        #pragma unroll
        for (int kk = 0; kk < 8; ++kk) {
            bf16x8 b = bs8[c * 512 + kk * 64 + lane];   // stride-1 ds_read_b128
            acc = __builtin_amdgcn_mfma_f32_32x32x16_bf16(a[kk], b, acc, 0, 0, 0);
        }
        // rows pre-scaled: acc = logit*log2e, bounded +-2.89 -> plain exp2
        float cacc = 0.0f;
        #pragma unroll
        for (int i = 0; i < 16; ++i) {
            float e = EXP2F(acc[i]);
            sums[i] += e;       // row-sum accumulation (col-reduced later)
            cacc    += e;       // this lane's column (c*32+ln) partial
        }
        if (c == 0) csum0 += cacc;
        else if (c == 1) csum1 += cacc;
        else if (c == 2) csum2 += cacc;
        else csum3 += cacc;
    }

    // row-path: multi-value butterfly (16 shfl total); lane ln ends up with
    // the full sum of row rloc(ln&15, h).
    {
        float r8[8], r4[4], r2[2], r1;
        #pragma unroll
        for (int i = 0; i < 8; ++i) {                 // offset 1: 16 -> 8
            float a0 = sums[2 * i], b0 = sums[2 * i + 1];
            float d = (ln & 1) ? a0 : b0;
            float e = __shfl_xor(d, 1, 64);
            r8[i] = ((ln & 1) ? b0 : a0) + e;
        }
        #pragma unroll
        for (int i = 0; i < 4; ++i) {                 // offset 2: 8 -> 4
            float a0 = r8[2 * i], b0 = r8[2 * i + 1];
            float d = (ln & 2) ? a0 : b0;
            float e = __shfl_xor(d, 2, 64);
            r4[i] = ((ln & 2) ? b0 : a0) + e;
        }
        #pragma unroll
        for (int i = 0; i < 2; ++i) {                 // offset 4: 4 -> 2
            float a0 = r4[2 * i], b0 = r4[2 * i + 1];
            float d = (ln & 4) ? a0 : b0;
            float e = __shfl_xor(d, 4, 64);
            r2[i] = ((ln & 4) ? b0 : a0) + e;
        }
        {                                             // offset 8: 2 -> 1
            float d = (ln & 8) ? r2[0] : r2[1];
            float e = __shfl_xor(d, 8, 64);
            r1 = ((ln & 8) ? r2[1] : r2[0]) + e;
        }
        r1 += __shfl_xor(r1, 16, 64);                 // fold the col-halves
        if (ln < 16) {
            const int rloc = (ln & 3) + 8 * (ln >> 2) + 4 * h;
            partials[(size_t)(row0 + rloc) * CSPLIT + cs] = r1;
        }
    }

    // col-path (off-diagonal only): combine h-halves, then the 4 waves via
    // LDS, write slot rb of the column rows.
    csum0 += __shfl_xor(csum0, 32, 64);
    csum1 += __shfl_xor(csum1, 32, 64);
    csum2 += __shfl_xor(csum2, 32, 64);
    csum3 += __shfl_xor(csum3, 32, 64);
    if (h == 0) {
        cls[wid][ln]      = csum0;
        cls[wid][32 + ln] = csum1;
        cls[wid][64 + ln] = csum2;
        cls[wid][96 + ln] = csum3;
    }
    __syncthreads();
    if (cs > rb && threadIdx.x < 128) {
        const int t = threadIdx.x;
        float v = cls[0][t] + cls[1][t] + cls[2][t] + cls[3][t];
        partials[(size_t)(cs * 128 + t) * CSPLIT + rb] = v;
    }

    // ---- completion counter: last NFIN blocks finalize ----
    __threadfence();                                  // release partials
    __syncthreads();                                  // all lanes' stores issued
    if (threadIdx.x == 0) s_old = atomicAdd(done, 1u);
    __syncthreads();
    const unsigned int old = s_old;
    if (old < NTILES - NFIN) return;

    if (threadIdx.x == 0) {
        while (__hip_atomic_load(done, __ATOMIC_RELAXED, __HIP_MEMORY_SCOPE_AGENT) < NTILES)
            __builtin_amdgcn_s_sleep(8);
    }
    __syncthreads();
    __threadfence();                                  // acquire partials

    // finalize a 256-row slice (former K3 logic, 64 rows per wave)
    const int slice = (int)old - (NTILES - NFIN);
    const int rowbase = slice * 256 + wid * 64;
    const int g = lane & 15;
    const int goff = ((g >> 1) << 6) + ((g & 1) << 5);

    float accv = 0.0f;
    for (int it = 0; it < 64; ++it) {
        const int r = rowbase + it;
        const int c = (r < B_ROWS) ? r : r - B_ROWS;   // label column
        float p = partials[(size_t)r * CSPLIT + lane];
        bf16x8 av = pk[(size_t)(r >> 5) * 512 + goff + (r & 31)];
        bf16x8 bv = pk[(size_t)(c >> 5) * 512 + goff + (c & 31)];
        float d = 0.0f;
        #pragma unroll
        for (int e = 0; e < 8; ++e) d += (float)av[e] * (float)bv[e];
        // 64-lane reduce: p -> row exp-sum; d -> 4 * SCALE_LOG2 * cos(r,c)
        #pragma unroll
        for (int off = 1; off < 64; off <<= 1) {
            d += __shfl_xor(d, off, 64);
            p += __shfl_xor(p, off, 64);
        }
        if (lane == 0) accv += logf(p) - d * LN2_OVER_4;
    }
    __syncthreads();          // cls no longer needed; reuse as reduce buffer
    if (lane == 0) cls[0][wid] = accv;
    __syncthreads();
    if (threadIdx.x == 0) {
        atomicAdd(out, (cls[0][0] + cls[0][1] + cls[0][2] + cls[0][3]) *
                       (1.0f / (float)N_ROWS));
    }
}

extern "C" void kernel_launch(void* const* d_in, const int* in_sizes, int n_in,
                              void* d_out, int out_size, void* d_ws, size_t ws_size,
                              hipStream_t stream) {
    const float* zi = (const float*)d_in[0];
    const float* zj = (const float*)d_in[1];
    float* out = (float*)d_out;

    __bf16* pack      = (__bf16*)d_ws;                                      // 2 MB
    float*  partials  = (float*)((char*)d_ws + (size_t)N_ROWS * D_DIM * 2); // 2 MB
    unsigned int* done = (unsigned int*)((char*)d_ws + 4u * 1024u * 1024u);

    k_normalize<<<dim3(N_ROWS / 4), dim3(256), 0, stream>>>(zi, zj, pack, out, done);
    k_gemm_expsum<<<dim3(NTILES), dim3(256), 0, stream>>>(pack, partials, done, out);
}

// Round 15
// 33.051 us; speedup vs baseline: 9.5090x; 9.5090x over previous
//
#include <hip/hip_runtime.h>
#include <hip/hip_bf16.h>
#include <math.h>

#define B_ROWS 4096
#define N_ROWS 8192
#define D_DIM  128
#define SCALE_LOG2 2.8853900817779268f   // (1/T)*log2(e)
#define PRESCALE 1.6986436f              // sqrt(SCALE_LOG2), folded into rows
#define LN2_OVER_4 0.17328679513998632f  // converts 4x-dup group dot -> 2*cos

#define CSPLIT 64
#define NTILES 2080                      // 64*65/2 upper-triangle 128x128 tiles

typedef __bf16 bf16x8 __attribute__((ext_vector_type(8)));
typedef __bf16 bf16x4 __attribute__((ext_vector_type(4)));
typedef float  f32x16 __attribute__((ext_vector_type(16)));

#if __has_builtin(__builtin_amdgcn_exp2f)
#define EXP2F(x) __builtin_amdgcn_exp2f(x)
#else
#define EXP2F(x) exp2f(x)
#endif

#define AS(n) __attribute__((address_space(n)))

// Packed fragment-major layout (16B chunk units), 32x32x16 MFMA:
//   chunk(p, kk, l) = zn[p*32 + (l&31)][ (kk*2 + (l>>5))*8 .. +8 ]   (8 bf16)
//   addr16B = p*512 + kk*64 + l
// one wave fragment load = 64 consecutive 16B chunks = 1KB coalesced.

// ---------- K1: normalize rows of concat(z_i, z_j) -> packed bf16 ----------
// float4 per lane: 32 lanes cover one row; each wave handles 2 rows (xor
// shuffle offsets <32 never cross the 32-lane halves). 8 rows/block.
// Block 0 also zeroes the output scalar (no memset node; K1 precedes K3).
__global__ __launch_bounds__(256) void k_normalize(const float* __restrict__ zi,
                                                   const float* __restrict__ zj,
                                                   __bf16* __restrict__ pack,
                                                   float* __restrict__ out) {
    if (blockIdx.x == 0 && threadIdx.x == 0) out[0] = 0.0f;
    const int wid  = threadIdx.x >> 6;
    const int lane = threadIdx.x & 63;
    const int half = lane >> 5;          // row within the wave's pair
    const int ln   = lane & 31;
    const int row  = blockIdx.x * 8 + wid * 2 + half;
    const float* src = (row < B_ROWS) ? (zi + (size_t)row * D_DIM)
                                      : (zj + (size_t)(row - B_ROWS) * D_DIM);
    float4 v = ((const float4*)src)[ln];
    float ss = v.x * v.x + v.y * v.y + v.z * v.z + v.w * v.w;
    #pragma unroll
    for (int off = 1; off < 32; off <<= 1) ss += __shfl_xor(ss, off, 64);
    float inv = PRESCALE / fmaxf(sqrtf(ss), 1e-8f);
    bf16x4 o;
    o[0] = (__bf16)(v.x * inv);
    o[1] = (__bf16)(v.y * inv);
    o[2] = (__bf16)(v.z * inv);
    o[3] = (__bf16)(v.w * inv);
    // elems e = 4*ln .. 4*ln+3: kk = ln>>2, h = (ln>>1)&1, lo/hi = ln&1
    const int chunk = ((row >> 5) << 9) + ((ln >> 2) << 6) +
                      (((ln >> 1) & 1) << 5) + (row & 31);
    ((bf16x4*)pack)[chunk * 2 + (ln & 1)] = o;
}

// ---------- K2: upper-triangle NT-GEMM with symmetric exp accumulation ----
// (R13 structure, verified 33.1us total) Exact 2080-block 1D grid, f32
// closed-form (rb,cs) decode (+-1 fixup loops absorb rounding). Async
// global_load_lds B-staging, one barrier, 4 col-tile chains, fused exp2;
// row-sums -> slot cs (multi-value butterfly, 16 shfl), col-sums (off-diag)
// -> slot rb via LDS combine.
__global__ __launch_bounds__(256, 4) void k_gemm_expsum(const __bf16* __restrict__ pack,
                                                        float* __restrict__ partials) {
    // decode linear upper-tri index u -> (rb, cs): S(r) = 64r - r(r-1)/2
    const int u = blockIdx.x;
    int rb = (int)((129.0f - sqrtf(16641.0f - 8.0f * (float)u)) * 0.5f);
    if (rb < 0) rb = 0;
    if (rb > 63) rb = 63;
    while (rb > 0 && 64 * rb - rb * (rb - 1) / 2 > u) --rb;
    while (rb < 63 && 64 * (rb + 1) - (rb + 1) * rb / 2 <= u) ++rb;
    const int cs = rb + (u - (64 * rb - rb * (rb - 1) / 2));

    const int wid  = threadIdx.x >> 6;
    const int lane = threadIdx.x & 63;
    const int h    = lane >> 5;    // lane half (k-group)
    const int ln   = lane & 31;

    __shared__ __bf16 Bs[16384];   // 32 KB = 4 col-panels x 512 chunks x 16B
    __shared__ float  cls[4][128]; // per-wave column sums

    const bf16x8* pk = (const bf16x8*)pack;   // 16B chunk units

    // 1a. async-stage B panel: packed panels [4cs, 4cs+3] -> LDS, linear.
    {
        const size_t gbase = (size_t)cs * 2048;
        #pragma unroll
        for (int q = 0; q < 8; ++q) {
            const int cidx = q * 256 + wid * 64;   // wave-uniform chunk index
            __builtin_amdgcn_global_load_lds(
                (const AS(1) void*)(pk + gbase + cidx + lane),
                (AS(3) void*)(Bs + (size_t)cidx * 8), 16, 0, 0);
        }
    }

    // 1b. A fragments (private, coalesced) - in flight during B staging
    const int row0 = rb * 128 + wid * 32;
    const size_t pa = (size_t)(row0 >> 5) * 512;
    bf16x8 a[8];
    #pragma unroll
    for (int kk = 0; kk < 8; ++kk)
        a[kk] = pk[pa + kk * 64 + lane];

    float sums[16];
    #pragma unroll
    for (int i = 0; i < 16; ++i) sums[i] = 0.0f;
    float csum0 = 0.0f, csum1 = 0.0f, csum2 = 0.0f, csum3 = 0.0f;

    // 2. one barrier (drains vmcnt: global_load_lds + A loads)
    __syncthreads();

    // 3. four independent col-tile compute chains
    const bf16x8* bs8 = (const bf16x8*)Bs;
    #pragma unroll
    for (int c = 0; c < 4; ++c) {
        f32x16 acc = {};
        #pragma unroll
        for (int kk = 0; kk < 8; ++kk) {
            bf16x8 b = bs8[c * 512 + kk * 64 + lane];   // stride-1 ds_read_b128
            acc = __builtin_amdgcn_mfma_f32_32x32x16_bf16(a[kk], b, acc, 0, 0, 0);
        }
        // rows pre-scaled: acc = logit*log2e, bounded +-2.89 -> plain exp2
        float cacc = 0.0f;
        #pragma unroll
        for (int i = 0; i < 16; ++i) {
            float e = EXP2F(acc[i]);
            sums[i] += e;       // row-sum accumulation (col-reduced later)
            cacc    += e;       // this lane's column (c*32+ln) partial
        }
        if (c == 0) csum0 += cacc;
        else if (c == 1) csum1 += cacc;
        else if (c == 2) csum2 += cacc;
        else csum3 += cacc;
    }

    // row-path: multi-value butterfly (16 shfl total); lane ln ends up with
    // the full sum of row rloc(ln&15, h).
    {
        float r8[8], r4[4], r2[2], r1;
        #pragma unroll
        for (int i = 0; i < 8; ++i) {                 // offset 1: 16 -> 8
            float a0 = sums[2 * i], b0 = sums[2 * i + 1];
            float d = (ln & 1) ? a0 : b0;
            float e = __shfl_xor(d, 1, 64);
            r8[i] = ((ln & 1) ? b0 : a0) + e;
        }
        #pragma unroll
        for (int i = 0; i < 4; ++i) {                 // offset 2: 8 -> 4
            float a0 = r8[2 * i], b0 = r8[2 * i + 1];
            float d = (ln & 2) ? a0 : b0;
            float e = __shfl_xor(d, 2, 64);
            r4[i] = ((ln & 2) ? b0 : a0) + e;
        }
        #pragma unroll
        for (int i = 0; i < 2; ++i) {                 // offset 4: 4 -> 2
            float a0 = r4[2 * i], b0 = r4[2 * i + 1];
            float d = (ln & 4) ? a0 : b0;
            float e = __shfl_xor(d, 4, 64);
            r2[i] = ((ln & 4) ? b0 : a0) + e;
        }
        {                                             // offset 8: 2 -> 1
            float d = (ln & 8) ? r2[0] : r2[1];
            float e = __shfl_xor(d, 8, 64);
            r1 = ((ln & 8) ? r2[1] : r2[0]) + e;
        }
        r1 += __shfl_xor(r1, 16, 64);                 // fold the col-halves
        if (ln < 16) {
            const int rloc = (ln & 3) + 8 * (ln >> 2) + 4 * h;
            partials[(size_t)(row0 + rloc) * CSPLIT + cs] = r1;
        }
    }

    // col-path (off-diagonal only): combine h-halves, then the 4 waves via
    // LDS, write slot rb of the column rows.
    csum0 += __shfl_xor(csum0, 32, 64);
    csum1 += __shfl_xor(csum1, 32, 64);
    csum2 += __shfl_xor(csum2, 32, 64);
    csum3 += __shfl_xor(csum3, 32, 64);
    if (h == 0) {
        cls[wid][ln]      = csum0;
        cls[wid][32 + ln] = csum1;
        cls[wid][64 + ln] = csum2;
        cls[wid][96 + ln] = csum3;
    }
    __syncthreads();
    if (cs > rb && threadIdx.x < 128) {
        const int t = threadIdx.x;
        float v = cls[0][t] + cls[1][t] + cls[2][t] + cls[3][t];
        partials[(size_t)(cs * 128 + t) * CSPLIT + rb] = v;
    }
}

// ---------- K3: merge partials + label logit + nll -> loss ----------
__global__ __launch_bounds__(256) void k_finalize(const __bf16* __restrict__ pack,
                                                  const float* __restrict__ partials,
                                                  float* __restrict__ out) {
    const int wid  = threadIdx.x >> 6;
    const int lane = threadIdx.x & 63;
    const int rowbase = blockIdx.x * 32 + wid * 8;
    const bf16x8* pk = (const bf16x8*)pack;

    const int g = lane & 15;
    const int goff = ((g >> 1) << 6) + ((g & 1) << 5);

    float accv = 0.0f;
    #pragma unroll
    for (int it = 0; it < 8; ++it) {
        const int r = rowbase + it;
        const int c = (r < B_ROWS) ? r : r - B_ROWS;   // label column
        float p = partials[(size_t)r * CSPLIT + lane];
        bf16x8 av = pk[(size_t)(r >> 5) * 512 + goff + (r & 31)];
        bf16x8 bv = pk[(size_t)(c >> 5) * 512 + goff + (c & 31)];
        float d = 0.0f;
        #pragma unroll
        for (int e = 0; e < 8; ++e) d += (float)av[e] * (float)bv[e];
        // 64-lane reduce: p -> row exp-sum; d -> 4 * SCALE_LOG2 * cos(r,c)
        #pragma unroll
        for (int off = 1; off < 64; off <<= 1) {
            d += __shfl_xor(d, off, 64);
            p += __shfl_xor(p, off, 64);
        }
        if (lane == 0) {
            // nll = ln(sum) - 2*cos = logf(p) - d * ln2/4
            accv += logf(p) - d * LN2_OVER_4;
        }
    }
    __shared__ float ls[4];
    if (lane == 0) ls[wid] = accv;
    __syncthreads();
    if (threadIdx.x == 0) {
        atomicAdd(out, (ls[0] + ls[1] + ls[2] + ls[3]) * (1.0f / (float)N_ROWS));
    }
}

extern "C" void kernel_launch(void* const* d_in, const int* in_sizes, int n_in,
                              void* d_out, int out_size, void* d_ws, size_t ws_size,
                              hipStream_t stream) {
    const float* zi = (const float*)d_in[0];
    const float* zj = (const float*)d_in[1];
    float* out = (float*)d_out;

    __bf16* pack     = (__bf16*)d_ws;                                      // 2 MB
    float*  partials = (float*)((char*)d_ws + (size_t)N_ROWS * D_DIM * 2); // 2 MB

    k_normalize<<<dim3(N_ROWS / 8), dim3(256), 0, stream>>>(zi, zj, pack, out);
    k_gemm_expsum<<<dim3(NTILES), dim3(256), 0, stream>>>(pack, partials);
    k_finalize<<<dim3(N_ROWS / 32), dim3(256), 0, stream>>>(pack, partials, out);
}